// Round 16
// baseline (294.729 us; speedup 1.0000x reference)
//
#include <hip/hip_runtime.h>

#define BATCH 32
#define CIN   256
#define CHALF 128
#define NPIX  3136   // 56*56
#define MPOOL 784    // 28*28
#define MPAD  896    // 784 padded to multiple of 32

typedef __bf16 bf16;
typedef __bf16 bf16x2 __attribute__((ext_vector_type(2)));
typedef __bf16 bf16x4 __attribute__((ext_vector_type(4)));
typedef __bf16 bf16x8 __attribute__((ext_vector_type(8)));
typedef float  f32x4  __attribute__((ext_vector_type(4)));

// ---------------------------------------------------------------------------
// k_cast: W1,W2,W3 fp32 -> WcatF frag-major bf16 (R15, unchanged)
// ---------------------------------------------------------------------------
__global__ __launch_bounds__(256) void k_cast(
    const float* __restrict__ W1, const float* __restrict__ W2,
    const float* __restrict__ W3, bf16* __restrict__ WcatF)
{
    int u = blockIdx.x * 256 + threadIdx.x;   // 0..16383
    int lane = u & 63, frag = u >> 6;
    int ks = frag & 7, ot = frag >> 3;
    int o = ot * 16 + (lane & 15);
    int c0 = ks * 32 + (lane >> 4) * 8;
    const float* src = (o < 128) ? (W1 + o * 256)
                     : (o < 256) ? (W2 + (o - 128) * 256)
                                 : (W3 + (o - 256) * 256);
    float4 v0 = *(const float4*)(src + c0);
    float4 v1 = *(const float4*)(src + c0 + 4);
    bf16x8 w = { (bf16)v0.x, (bf16)v0.y, (bf16)v0.z, (bf16)v0.w,
                 (bf16)v1.x, (bf16)v1.y, (bf16)v1.z, (bf16)v1.w };
    *(bf16x8*)(WcatF + (size_t)u * 8) = w;
}

// ---------------------------------------------------------------------------
// k_conv (R15, unchanged): MFMA 1x1 convs + fused 2x2 max+avg pool.
// ---------------------------------------------------------------------------
#define XS_STRIDE   528
#define SLAB_STRIDE 520

__global__ __launch_bounds__(512) void k_conv(
    const float* __restrict__ x, const bf16* __restrict__ WcatF,
    bf16* __restrict__ c2n, bf16* __restrict__ c1pT, bf16* __restrict__ c3p)
{
    const int h2 = blockIdx.x, b = blockIdx.y;
    const int t = threadIdx.x;
    const int lane = t & 63, wave = t >> 6;
    const int l15 = lane & 15, lg = lane >> 4;

    __shared__ __align__(16) unsigned char smem[59136];

    if (h2 == 0) {
        float4 z = {0.f, 0.f, 0.f, 0.f};
        float4* p1 = (float4*)(c1pT + (size_t)b * MPAD * CHALF + (size_t)MPOOL * CHALF);
        for (int u = t; u < 1792; u += 512) p1[u] = z;
        bf16* p3 = c3p + (size_t)b * CIN * MPAD + MPOOL;
        for (int u = t; u < 256 * 14; u += 512) {
            int c = u / 14, g = u % 14;
            *(float4*)((char*)(p3 + (size_t)c * MPAD) + g * 16) = z;
        }
    }

    {
        const float* xb = x + (size_t)b * CIN * NPIX + h2 * 112;
        float vv[14][4];
        #pragma unroll
        for (int i = 0; i < 14; ++i) {
            int u = t + i * 512;
            int c4 = u / 112, n = u - c4 * 112;
            const float* s = xb + (size_t)(c4 * 4) * NPIX + n;
            vv[i][0] = s[0];
            vv[i][1] = s[NPIX];
            vv[i][2] = s[2 * NPIX];
            vv[i][3] = s[3 * NPIX];
        }
        #pragma unroll
        for (int i = 0; i < 14; ++i) {
            int u = t + i * 512;
            int c4 = u / 112, n = u - c4 * 112;
            bf16x4 w = {(bf16)vv[i][0], (bf16)vv[i][1], (bf16)vv[i][2], (bf16)vv[i][3]};
            *(bf16x4*)(smem + n * XS_STRIDE + c4 * 8) = w;
        }
    }
    __syncthreads();

    f32x4 acc[4][7];
    #pragma unroll
    for (int fo = 0; fo < 4; ++fo)
        #pragma unroll
        for (int fn = 0; fn < 7; ++fn) {
            f32x4 zz = {0.f, 0.f, 0.f, 0.f};
            acc[fo][fn] = zz;
        }
    {
        const unsigned char* xsb = smem + l15 * XS_STRIDE + lg * 16;
        const bf16* wfb = WcatF + (((size_t)wave * 4) * 8 + 0) * 64 * 8 + (size_t)lane * 8;
        #pragma unroll
        for (int ks = 0; ks < 8; ++ks) {
            bf16x8 afr[4], bfr[7];
            #pragma unroll
            for (int fo = 0; fo < 4; ++fo)
                afr[fo] = *(const bf16x8*)(wfb + (size_t)(fo * 8 + ks) * 64 * 8);
            #pragma unroll
            for (int fn = 0; fn < 7; ++fn)
                bfr[fn] = *(const bf16x8*)(xsb + fn * 16 * XS_STRIDE + ks * 64);
            #pragma unroll
            for (int fo = 0; fo < 4; ++fo)
                #pragma unroll
                for (int fn = 0; fn < 7; ++fn)
                    acc[fo][fn] = __builtin_amdgcn_mfma_f32_16x16x32_bf16(
                        afr[fo], bfr[fn], acc[fo][fn], 0, 0, 0);
        }
    }

    __syncthreads();
    if (wave < 4) {
        #pragma unroll
        for (int fo = 0; fo < 4; ++fo)
            #pragma unroll
            for (int fn = 0; fn < 7; ++fn) {
                int n = fn * 16 + l15;
                int ol = wave * 64 + fo * 16 + lg * 4;
                f32x4 a = acc[fo][fn];
                bf16x4 w = {(bf16)a[0], (bf16)a[1], (bf16)a[2], (bf16)a[3]};
                *(bf16x4*)(smem + n * SLAB_STRIDE + ol * 2) = w;
            }
    }
    __syncthreads();
    {
        bf16* dst = c1pT + (size_t)b * MPAD * CHALF + (size_t)h2 * 28 * CHALF;
        for (int u = t; u < 896; u += 512) {
            int w2 = u >> 5, o4 = (u & 31) * 4;
            bf16x4 r0 = *(bf16x4*)(smem + (2 * w2)      * SLAB_STRIDE + o4 * 2);
            bf16x4 r1 = *(bf16x4*)(smem + (2 * w2 + 1)  * SLAB_STRIDE + o4 * 2);
            bf16x4 r2 = *(bf16x4*)(smem + (56 + 2 * w2) * SLAB_STRIDE + o4 * 2);
            bf16x4 r3 = *(bf16x4*)(smem + (57 + 2 * w2) * SLAB_STRIDE + o4 * 2);
            bf16x4 o_;
            #pragma unroll
            for (int j = 0; j < 4; ++j) {
                float p0 = (float)r0[j], p1 = (float)r1[j];
                float p2 = (float)r2[j], p3 = (float)r3[j];
                float mx = fmaxf(fmaxf(p0, p1), fmaxf(p2, p3));
                float av = (p0 + p1 + p2 + p3) * 0.25f;
                o_[j] = (bf16)(mx + av);
            }
            *(bf16x4*)(dst + (size_t)w2 * CHALF + o4) = o_;
        }
    }
    {
        bf16* dst = c2n + (size_t)b * NPIX * CHALF + (size_t)h2 * 112 * CHALF;
        for (int u = t; u < 3584; u += 512) {
            int n = u >> 5, o4 = (u & 31) * 4;
            bf16x4 v = *(bf16x4*)(smem + n * SLAB_STRIDE + 256 + o4 * 2);
            *(bf16x4*)(dst + (size_t)n * CHALF + o4) = v;
        }
    }

    __syncthreads();
    if (wave >= 4) {
        #pragma unroll
        for (int fo = 0; fo < 4; ++fo)
            #pragma unroll
            for (int fn = 0; fn < 7; ++fn) {
                int n = fn * 16 + l15;
                int ol = (wave - 4) * 64 + fo * 16 + lg * 4;
                f32x4 a = acc[fo][fn];
                bf16x4 w = {(bf16)a[0], (bf16)a[1], (bf16)a[2], (bf16)a[3]};
                *(bf16x4*)(smem + n * SLAB_STRIDE + ol * 2) = w;
            }
    }
    __syncthreads();
    {
        bf16* dst = c3p + (size_t)b * CIN * MPAD + h2 * 28;
        for (int u = t; u < 3584; u += 512) {
            int c = u / 14, w2p = u - c * 14;
            bf16x2 o_;
            #pragma unroll
            for (int k = 0; k < 2; ++k) {
                int w2 = 2 * w2p + k;
                float p0 = (float)*(bf16*)(smem + (2 * w2)      * SLAB_STRIDE + c * 2);
                float p1 = (float)*(bf16*)(smem + (2 * w2 + 1)  * SLAB_STRIDE + c * 2);
                float p2 = (float)*(bf16*)(smem + (56 + 2 * w2) * SLAB_STRIDE + c * 2);
                float p3 = (float)*(bf16*)(smem + (57 + 2 * w2) * SLAB_STRIDE + c * 2);
                float mx = fmaxf(fmaxf(p0, p1), fmaxf(p2, p3));
                float av = (p0 + p1 + p2 + p3) * 0.25f;
                o_[k] = (bf16)(mx + av);
            }
            *(bf16x2*)(dst + (size_t)c * MPAD + 2 * w2p) = o_;
        }
    }
}

// ---------------------------------------------------------------------------
// k_attn v13: nt=32 for 2 blocks/CU (73 KB LDS), all proven components kept.
// S: waves (p=wave&1: 16-n frag, ms=wave>>1: m-frag interleave). c1pT staged
//    in 2x16KB dbuf carved from the (dead during S) P region; 64-m chunks.
// softmax in-register, 4-wave EX combine.  P pack = v8 formula (nt=32 rows).
// PV: waves (wq=wave>>1: 64-c, nd=wave&1: 16-n frag). V staged single 16KB
//    buffer (32-m chunks), v11 (c>>1)&3 involution. No cross-wave reduction.
// LDS: P 56KB @0 (S-dbuf overlays 0..32KB) | V-stage 16KB @57344 | EX @73728.
// ---------------------------------------------------------------------------
#define PVSTG 57344

__global__ __launch_bounds__(512, 2) void k_attn(
    const bf16* __restrict__ c2n,
    const bf16* __restrict__ c1pT,
    const bf16* __restrict__ c3p,
    const float* __restrict__ x,
    const float* __restrict__ gamma,
    float* __restrict__ out)
{
    const int nb = blockIdx.x, b = blockIdx.y;
    const int n0 = nb * 32;
    const int t = threadIdx.x;
    const int lane = t & 63, wave = t >> 6;
    const int l15 = lane & 15, lg = lane >> 4;
    const int p = wave & 1, ms = wave >> 1;

    __shared__ __align__(16) unsigned char smem[74752];
    unsigned char* stg0 = smem;                 // S dbuf (P region, dead now)
    unsigned char* stg1 = smem + 16384;
    unsigned char* vstg = smem + PVSTG;         // PV stage 16 KB
    float* EX = (float*)(smem + PVSTG + 16384); // 1 KB

    // ---- B-frags: c2 columns for n = n0 + p*16 + l15 (regs, loaded once) ---
    bf16x8 bq[4];
    {
        const bf16* c2b = c2n + ((size_t)b * NPIX + n0 + p * 16 + l15) * CHALF + lg * 8;
        #pragma unroll
        for (int k = 0; k < 4; ++k) bq[k] = *(const bf16x8*)(c2b + k * 32);
    }
    const bf16* c1b = c1pT + (size_t)b * MPAD * CHALF;
    const bf16* c3b = c3p + (size_t)b * CIN * MPAD;

    // ---- S staging: chunk = 64 m-rows x [16 slots x 16B] = 16 KB, dbuf -----
    const int r0 = t >> 4, s0 = t & 15;
    const int cs = (s0 & 8) | ((s0 & 7) ^ (r0 & 7));
    const bf16* sA = c1b + (size_t)r0 * CHALF + cs * 8;          // rows 0..31
    const bf16* sB = c1b + (size_t)(32 + r0) * CHALF + cs * 8;   // rows 32..63

    uint4 rXa, rXb, rYa, rYb;
    rXa = *(const uint4*)(sA);
    rXb = *(const uint4*)(sB);
    *(uint4*)(stg0 + t * 16) = rXa;
    *(uint4*)(stg0 + 8192 + t * 16) = rXb;
    rYa = *(const uint4*)(sA + 8192);
    rYb = *(const uint4*)(sB + 8192);
    __syncthreads();

    f32x4 sacc[14];
    #pragma unroll
    for (int j = 0; j < 14; ++j) {
        f32x4 z = {0.f, 0.f, 0.f, 0.f};
        sacc[j] = z;
    }

    #pragma unroll
    for (int j = 0; j < 14; ++j) {
        const unsigned char* bufc = (j & 1) ? stg1 : stg0;
        unsigned char* bufn = (j & 1) ? stg0 : stg1;
        if (j + 1 < 14) {
            if (j & 1) { *(uint4*)(bufn + t * 16) = rXa; *(uint4*)(bufn + 8192 + t * 16) = rXb; }
            else       { *(uint4*)(bufn + t * 16) = rYa; *(uint4*)(bufn + 8192 + t * 16) = rYb; }
        }
        if (j + 2 < 14) {
            if (j & 1) { rYa = *(const uint4*)(sA + (j + 2) * 8192); rYb = *(const uint4*)(sB + (j + 2) * 8192); }
            else       { rXa = *(const uint4*)(sA + (j + 2) * 8192); rXb = *(const uint4*)(sB + (j + 2) * 8192); }
        }
        // consume m-frag ms of this chunk
        {
            bf16x8 af[4];
            #pragma unroll
            for (int k = 0; k < 4; ++k)
                af[k] = *(const bf16x8*)(bufc + (ms * 16 + l15) * 256
                                         + ((lg * 16 + k * 64) ^ ((l15 & 7) << 4)));
            #pragma unroll
            for (int k = 0; k < 4; ++k)
                sacc[j] = __builtin_amdgcn_mfma_f32_16x16x32_bf16(af[k], bq[k], sacc[j], 0, 0, 0);
        }
        __syncthreads();
    }

    // ---- in-register softmax; valid frag iff (j<12) || (j==12 && ms==0) ----
    float mx = -1e30f;
    #pragma unroll
    for (int j = 0; j < 14; ++j) {
        if (j < 12 || (j == 12 && ms == 0))
            mx = fmaxf(mx, fmaxf(fmaxf(sacc[j][0], sacc[j][1]),
                                 fmaxf(sacc[j][2], sacc[j][3])));
    }
    mx = fmaxf(mx, __shfl_xor(mx, 16));
    mx = fmaxf(mx, __shfl_xor(mx, 32));
    if (lane < 16) EX[wave * 16 + l15] = mx;
    __syncthreads();
    {
        float m0 = EX[(p)     * 16 + l15], m1 = EX[(2 + p) * 16 + l15];
        float m2 = EX[(4 + p) * 16 + l15], m3 = EX[(6 + p) * 16 + l15];
        mx = fmaxf(fmaxf(m0, m1), fmaxf(m2, m3));
    }
    float s = 0.f;
    #pragma unroll
    for (int j = 0; j < 14; ++j) {
        if (j < 12 || (j == 12 && ms == 0)) {
            #pragma unroll
            for (int r = 0; r < 4; ++r) {
                float e = __expf(sacc[j][r] - mx);
                sacc[j][r] = e;
                s += e;
            }
        }
    }
    s += __shfl_xor(s, 16);
    s += __shfl_xor(s, 32);
    if (lane < 16) EX[128 + wave * 16 + l15] = s;
    __syncthreads();
    {
        float s0v = EX[128 + (p)     * 16 + l15], s1v = EX[128 + (2 + p) * 16 + l15];
        float s2v = EX[128 + (4 + p) * 16 + l15], s3v = EX[128 + (6 + p) * 16 + l15];
        s = (s0v + s1v) + (s2v + s3v);
    }
    const float ri = 1.f / s;

    // ---- pre-issue PV V chunk 0 (hide under pack + barrier) ----------------
    const int pc = t >> 2, ps = t & 3;
    const bf16* sV  = c3b + (size_t)pc * MPAD + ((ps ^ ((pc >> 1) & 3)) * 8);
    const bf16* sV2 = c3b + (size_t)(pc + 128) * MPAD + ((ps ^ ((pc >> 1) & 3)) * 8);
    rXa = *(const uint4*)(sV);
    rXb = *(const uint4*)(sV2);

    // ---- pack normalized P bf16 -> P_lds (swizzled b64 per frag) -----------
    {
        const int n = p * 16 + l15;
        const unsigned sw = (unsigned)((n & 7) << 4);
        const unsigned rowb = (unsigned)(n * 1792);
        #pragma unroll
        for (int j = 0; j < 14; ++j) {
            bf16x4 w;
            if (j < 12 || (j == 12 && ms == 0)) {
                w = bf16x4{ (bf16)(sacc[j][0] * ri), (bf16)(sacc[j][1] * ri),
                            (bf16)(sacc[j][2] * ri), (bf16)(sacc[j][3] * ri) };
            } else {
                w = bf16x4{ (bf16)0.f, (bf16)0.f, (bf16)0.f, (bf16)0.f };
            }
            unsigned byte = rowb + (unsigned)(j * 128 + ms * 32 + lg * 8);
            *(bf16x4*)(smem + (byte ^ sw)) = w;
        }
    }

    // ---- PV: single 16KB V buffer, 32-m chunks, 2 barriers per chunk -------
    const int wq = wave >> 1, nd = wave & 1;
    f32x4 acc2[4];
    #pragma unroll
    for (int fc = 0; fc < 4; ++fc) {
        f32x4 z = {0.f, 0.f, 0.f, 0.f};
        acc2[fc] = z;
    }
    const int nA = nd * 16 + l15;
    const unsigned swA = (unsigned)((nA & 7) << 4);
    const unsigned rbA = (unsigned)(nA * 1792);

    #pragma unroll
    for (int ks = 0; ks < 28; ++ks) {
        __syncthreads();    // previous chunk consumed (and P pack complete at ks=0)
        *(uint4*)(vstg + t * 16) = (ks & 1) ? rYa : rXa;
        *(uint4*)(vstg + 8192 + t * 16) = (ks & 1) ? rYb : rXb;
        if (ks + 1 < 28) {
            if (ks & 1) { rXa = *(const uint4*)(sV + (ks + 1) * 32); rXb = *(const uint4*)(sV2 + (ks + 1) * 32); }
            else        { rYa = *(const uint4*)(sV + (ks + 1) * 32); rYb = *(const uint4*)(sV2 + (ks + 1) * 32); }
        }
        __syncthreads();    // buffer ready
        {
            bf16x8 af = *(const bf16x8*)(smem + ((rbA + (unsigned)(ks * 64 + lg * 16)) ^ swA));
            #pragma unroll
            for (int fc = 0; fc < 4; ++fc) {
                int c = wq * 64 + fc * 16 + l15;
                bf16x8 bfr = *(const bf16x8*)(vstg + c * 64 + ((lg ^ ((c >> 1) & 3)) * 16));
                acc2[fc] = __builtin_amdgcn_mfma_f32_16x16x32_bf16(af, bfr, acc2[fc], 0, 0, 0);
            }
        }
    }

    // ---- epilogue: R[32][257] transpose, out = g*refined + x ---------------
    __syncthreads();    // all P reads done before overwrite
    float* R = (float*)smem;
    #pragma unroll
    for (int fc = 0; fc < 4; ++fc) {
        int c = wq * 64 + fc * 16 + lg * 4;
        #pragma unroll
        for (int r = 0; r < 4; ++r)
            R[(nd * 16 + l15) * 257 + c + r] = acc2[fc][r];
    }
    __syncthreads();
    const float g = gamma[0];
    const float* xb = x + (size_t)b * CIN * NPIX + n0;
    float* ob = out + (size_t)b * CIN * NPIX + n0;
    #pragma unroll 4
    for (int i = 0; i < 16; ++i) {
        int idx = t + i * 512;                  // 256 c x 32 n
        int c = idx >> 5, nn = idx & 31;
        size_t off = (size_t)c * NPIX + nn;
        ob[off] = g * R[nn * 257 + c] + xb[off];
    }
}

extern "C" void kernel_launch(void* const* d_in, const int* in_sizes, int n_in,
                              void* d_out, int out_size, void* d_ws, size_t ws_size,
                              hipStream_t stream) {
    const float* x     = (const float*)d_in[0];
    const float* W1    = (const float*)d_in[1];
    const float* W2    = (const float*)d_in[2];
    const float* W3    = (const float*)d_in[3];
    const float* gamma = (const float*)d_in[4];
    float* out = (float*)d_out;

    bf16* ws    = (bf16*)d_ws;
    bf16* WcatF = ws;                                      // 512*256 (frag-major)
    bf16* c2n   = WcatF + (size_t)512 * 256;               // 32*3136*128
    bf16* c1pT  = c2n + (size_t)BATCH * NPIX * CHALF;      // 32*896*128
    bf16* c3p   = c1pT + (size_t)BATCH * MPAD * CHALF;     // 32*256*896

    k_cast<<<64, 256, 0, stream>>>(W1, W2, W3, WcatF);
    k_conv<<<dim3(28, BATCH), 512, 0, stream>>>(x, WcatF, c2n, c1pT, c3p);
    k_attn<<<dim3(98, BATCH), 512, 0, stream>>>(c2n, c1pT, c3p, x, gamma, out);
}

// Round 17
// 239.754 us; speedup vs baseline: 1.2293x; 1.2293x over previous
//
#include <hip/hip_runtime.h>

#define BATCH 32
#define CIN   256
#define CHALF 128
#define NPIX  3136   // 56*56
#define MPOOL 784    // 28*28
#define MPAD  896    // 784 padded to multiple of 32

typedef __bf16 bf16;
typedef __bf16 bf16x2 __attribute__((ext_vector_type(2)));
typedef __bf16 bf16x4 __attribute__((ext_vector_type(4)));
typedef __bf16 bf16x8 __attribute__((ext_vector_type(8)));
typedef float  f32x4  __attribute__((ext_vector_type(4)));

// ---------------------------------------------------------------------------
// k_cast: W1,W2,W3 fp32 -> WcatF frag-major bf16.
// WcatF entry (ot, ks, lane) = W[ot*16 + (lane&15)][ks*32 + (lane>>4)*8 .. +7]
// so a wave's MFMA A-frag load is lane*16B contiguous (1 KB coalesced).
// ---------------------------------------------------------------------------
__global__ __launch_bounds__(256) void k_cast(
    const float* __restrict__ W1, const float* __restrict__ W2,
    const float* __restrict__ W3, bf16* __restrict__ WcatF)
{
    int u = blockIdx.x * 256 + threadIdx.x;   // 0..16383
    int lane = u & 63, frag = u >> 6;
    int ks = frag & 7, ot = frag >> 3;
    int o = ot * 16 + (lane & 15);
    int c0 = ks * 32 + (lane >> 4) * 8;
    const float* src = (o < 128) ? (W1 + o * 256)
                     : (o < 256) ? (W2 + (o - 128) * 256)
                                 : (W3 + (o - 256) * 256);
    float4 v0 = *(const float4*)(src + c0);
    float4 v1 = *(const float4*)(src + c0 + 4);
    bf16x8 w = { (bf16)v0.x, (bf16)v0.y, (bf16)v0.z, (bf16)v0.w,
                 (bf16)v1.x, (bf16)v1.y, (bf16)v1.z, (bf16)v1.w };
    *(bf16x8*)(WcatF + (size_t)u * 8) = w;
}

// ---------------------------------------------------------------------------
// k_conv (R15): MFMA 1x1 convs + fused 2x2 max+avg pool; frag-major weights.
// ---------------------------------------------------------------------------
#define XS_STRIDE   528
#define SLAB_STRIDE 520

__global__ __launch_bounds__(512) void k_conv(
    const float* __restrict__ x, const bf16* __restrict__ WcatF,
    bf16* __restrict__ c2n, bf16* __restrict__ c1pT, bf16* __restrict__ c3p)
{
    const int h2 = blockIdx.x, b = blockIdx.y;
    const int t = threadIdx.x;
    const int lane = t & 63, wave = t >> 6;
    const int l15 = lane & 15, lg = lane >> 4;

    __shared__ __align__(16) unsigned char smem[59136];

    if (h2 == 0) {
        float4 z = {0.f, 0.f, 0.f, 0.f};
        float4* p1 = (float4*)(c1pT + (size_t)b * MPAD * CHALF + (size_t)MPOOL * CHALF);
        for (int u = t; u < 1792; u += 512) p1[u] = z;
        bf16* p3 = c3p + (size_t)b * CIN * MPAD + MPOOL;
        for (int u = t; u < 256 * 14; u += 512) {
            int c = u / 14, g = u % 14;
            *(float4*)((char*)(p3 + (size_t)c * MPAD) + g * 16) = z;
        }
    }

    {
        const float* xb = x + (size_t)b * CIN * NPIX + h2 * 112;
        float vv[14][4];
        #pragma unroll
        for (int i = 0; i < 14; ++i) {
            int u = t + i * 512;
            int c4 = u / 112, n = u - c4 * 112;
            const float* s = xb + (size_t)(c4 * 4) * NPIX + n;
            vv[i][0] = s[0];
            vv[i][1] = s[NPIX];
            vv[i][2] = s[2 * NPIX];
            vv[i][3] = s[3 * NPIX];
        }
        #pragma unroll
        for (int i = 0; i < 14; ++i) {
            int u = t + i * 512;
            int c4 = u / 112, n = u - c4 * 112;
            bf16x4 w = {(bf16)vv[i][0], (bf16)vv[i][1], (bf16)vv[i][2], (bf16)vv[i][3]};
            *(bf16x4*)(smem + n * XS_STRIDE + c4 * 8) = w;
        }
    }
    __syncthreads();

    f32x4 acc[4][7];
    #pragma unroll
    for (int fo = 0; fo < 4; ++fo)
        #pragma unroll
        for (int fn = 0; fn < 7; ++fn) {
            f32x4 zz = {0.f, 0.f, 0.f, 0.f};
            acc[fo][fn] = zz;
        }
    {
        const unsigned char* xsb = smem + l15 * XS_STRIDE + lg * 16;
        const bf16* wfb = WcatF + (((size_t)wave * 4) * 8 + 0) * 64 * 8 + (size_t)lane * 8;
        #pragma unroll
        for (int ks = 0; ks < 8; ++ks) {
            bf16x8 afr[4], bfr[7];
            #pragma unroll
            for (int fo = 0; fo < 4; ++fo)
                afr[fo] = *(const bf16x8*)(wfb + (size_t)(fo * 8 + ks) * 64 * 8);
            #pragma unroll
            for (int fn = 0; fn < 7; ++fn)
                bfr[fn] = *(const bf16x8*)(xsb + fn * 16 * XS_STRIDE + ks * 64);
            #pragma unroll
            for (int fo = 0; fo < 4; ++fo)
                #pragma unroll
                for (int fn = 0; fn < 7; ++fn)
                    acc[fo][fn] = __builtin_amdgcn_mfma_f32_16x16x32_bf16(
                        afr[fo], bfr[fn], acc[fo][fn], 0, 0, 0);
        }
    }

    __syncthreads();
    if (wave < 4) {
        #pragma unroll
        for (int fo = 0; fo < 4; ++fo)
            #pragma unroll
            for (int fn = 0; fn < 7; ++fn) {
                int n = fn * 16 + l15;
                int ol = wave * 64 + fo * 16 + lg * 4;
                f32x4 a = acc[fo][fn];
                bf16x4 w = {(bf16)a[0], (bf16)a[1], (bf16)a[2], (bf16)a[3]};
                *(bf16x4*)(smem + n * SLAB_STRIDE + ol * 2) = w;
            }
    }
    __syncthreads();
    {
        bf16* dst = c1pT + (size_t)b * MPAD * CHALF + (size_t)h2 * 28 * CHALF;
        for (int u = t; u < 896; u += 512) {
            int w2 = u >> 5, o4 = (u & 31) * 4;
            bf16x4 r0 = *(bf16x4*)(smem + (2 * w2)      * SLAB_STRIDE + o4 * 2);
            bf16x4 r1 = *(bf16x4*)(smem + (2 * w2 + 1)  * SLAB_STRIDE + o4 * 2);
            bf16x4 r2 = *(bf16x4*)(smem + (56 + 2 * w2) * SLAB_STRIDE + o4 * 2);
            bf16x4 r3 = *(bf16x4*)(smem + (57 + 2 * w2) * SLAB_STRIDE + o4 * 2);
            bf16x4 o_;
            #pragma unroll
            for (int j = 0; j < 4; ++j) {
                float p0 = (float)r0[j], p1 = (float)r1[j];
                float p2 = (float)r2[j], p3 = (float)r3[j];
                float mx = fmaxf(fmaxf(p0, p1), fmaxf(p2, p3));
                float av = (p0 + p1 + p2 + p3) * 0.25f;
                o_[j] = (bf16)(mx + av);
            }
            *(bf16x4*)(dst + (size_t)w2 * CHALF + o4) = o_;
        }
    }
    {
        bf16* dst = c2n + (size_t)b * NPIX * CHALF + (size_t)h2 * 112 * CHALF;
        for (int u = t; u < 3584; u += 512) {
            int n = u >> 5, o4 = (u & 31) * 4;
            bf16x4 v = *(bf16x4*)(smem + n * SLAB_STRIDE + 256 + o4 * 2);
            *(bf16x4*)(dst + (size_t)n * CHALF + o4) = v;
        }
    }

    __syncthreads();
    if (wave >= 4) {
        #pragma unroll
        for (int fo = 0; fo < 4; ++fo)
            #pragma unroll
            for (int fn = 0; fn < 7; ++fn) {
                int n = fn * 16 + l15;
                int ol = (wave - 4) * 64 + fo * 16 + lg * 4;
                f32x4 a = acc[fo][fn];
                bf16x4 w = {(bf16)a[0], (bf16)a[1], (bf16)a[2], (bf16)a[3]};
                *(bf16x4*)(smem + n * SLAB_STRIDE + ol * 2) = w;
            }
    }
    __syncthreads();
    {
        bf16* dst = c3p + (size_t)b * CIN * MPAD + h2 * 28;
        for (int u = t; u < 3584; u += 512) {
            int c = u / 14, w2p = u - c * 14;
            bf16x2 o_;
            #pragma unroll
            for (int k = 0; k < 2; ++k) {
                int w2 = 2 * w2p + k;
                float p0 = (float)*(bf16*)(smem + (2 * w2)      * SLAB_STRIDE + c * 2);
                float p1 = (float)*(bf16*)(smem + (2 * w2 + 1)  * SLAB_STRIDE + c * 2);
                float p2 = (float)*(bf16*)(smem + (56 + 2 * w2) * SLAB_STRIDE + c * 2);
                float p3 = (float)*(bf16*)(smem + (57 + 2 * w2) * SLAB_STRIDE + c * 2);
                float mx = fmaxf(fmaxf(p0, p1), fmaxf(p2, p3));
                float av = (p0 + p1 + p2 + p3) * 0.25f;
                o_[k] = (bf16)(mx + av);
            }
            *(bf16x2*)(dst + (size_t)c * MPAD + 2 * w2p) = o_;
        }
    }
}

// ---------------------------------------------------------------------------
// k_attn v11 (R14, best measured: 180 us): nt=64, staged S + in-register
// softmax + single P pack + double-buffered PV staging with (c>>1)&3
// involution. Natural grid (49, b) — XCD swizzle measured neutral (R15).
// ---------------------------------------------------------------------------
#define STG_OFF 114688

__global__ __launch_bounds__(512) void k_attn(
    const bf16* __restrict__ c2n,
    const bf16* __restrict__ c1pT,
    const bf16* __restrict__ c3p,
    const float* __restrict__ x,
    const float* __restrict__ gamma,
    float* __restrict__ out)
{
    const int nb = blockIdx.x, b = blockIdx.y;
    const int n0 = nb * 64;
    const int t = threadIdx.x;
    const int lane = t & 63, wave = t >> 6;
    const int l15 = lane & 15, lg = lane >> 4;
    const int p = wave & 3, h = wave >> 2;

    __shared__ __align__(16) unsigned char smem[147456];
    unsigned char* stg = smem + STG_OFF;
    float* EX = (float*)stg;

    bf16x8 bq[4];
    {
        const bf16* c2b = c2n + ((size_t)b * NPIX + n0 + p * 16 + l15) * CHALF + lg * 8;
        #pragma unroll
        for (int k = 0; k < 4; ++k) bq[k] = *(const bf16x8*)(c2b + k * 32);
    }
    const bf16* c1b = c1pT + (size_t)b * MPAD * CHALF;
    const bf16* c3b = c3p + (size_t)b * CIN * MPAD;

    const int r0 = t >> 4, s0 = t & 15;
    const int cs = (s0 & 8) | ((s0 & 7) ^ (r0 & 7));
    const bf16* sA = c1b + (size_t)r0 * CHALF + cs * 8;
    const bf16* sB = c1b + (size_t)(448 + r0) * CHALF + cs * 8;

    uint4 rXa, rXb, rYa, rYb;
    rXa = *(const uint4*)(sA);
    rXb = *(const uint4*)(sB);
    *(uint4*)(stg + t * 16) = rXa;
    *(uint4*)(stg + 8192 + t * 16) = rXb;
    rYa = *(const uint4*)(sA + 4096);
    rYb = *(const uint4*)(sB + 4096);
    __syncthreads();

    f32x4 sacc[28];
    #pragma unroll
    for (int j = 0; j < 28; ++j) {
        f32x4 z = {0.f, 0.f, 0.f, 0.f};
        sacc[j] = z;
    }

    #pragma unroll
    for (int mc = 0; mc < 14; ++mc) {
        const unsigned char* bufc = stg + (mc & 1) * 16384;
        unsigned char* bufn = stg + ((mc & 1) ^ 1) * 16384;
        if (mc + 1 < 14) {
            if (mc & 1) { *(uint4*)(bufn + t * 16) = rXa; *(uint4*)(bufn + 8192 + t * 16) = rXb; }
            else        { *(uint4*)(bufn + t * 16) = rYa; *(uint4*)(bufn + 8192 + t * 16) = rYb; }
        }
        if (mc + 2 < 14) {
            if (mc & 1) { rYa = *(const uint4*)(sA + (mc + 2) * 4096); rYb = *(const uint4*)(sB + (mc + 2) * 4096); }
            else        { rXa = *(const uint4*)(sA + (mc + 2) * 4096); rXb = *(const uint4*)(sB + (mc + 2) * 4096); }
        }
        #pragma unroll
        for (int sf = 0; sf < 2; ++sf) {
            bf16x8 af[4];
            #pragma unroll
            for (int k = 0; k < 4; ++k)
                af[k] = *(const bf16x8*)(bufc + h * 8192 + (sf * 16 + l15) * 256
                                         + ((lg * 16 + k * 64) ^ ((l15 & 7) << 4)));
            #pragma unroll
            for (int k = 0; k < 4; ++k)
                sacc[mc * 2 + sf] = __builtin_amdgcn_mfma_f32_16x16x32_bf16(
                    af[k], bq[k], sacc[mc * 2 + sf], 0, 0, 0);
        }
        __syncthreads();
    }

    float mx = -1e30f;
    #pragma unroll
    for (int j = 0; j < 28; ++j) {
        if (h == 0 || j < 21)
            mx = fmaxf(mx, fmaxf(fmaxf(sacc[j][0], sacc[j][1]),
                                 fmaxf(sacc[j][2], sacc[j][3])));
    }
    mx = fmaxf(mx, __shfl_xor(mx, 16));
    mx = fmaxf(mx, __shfl_xor(mx, 32));
    if (lane < 16) EX[wave * 16 + l15] = mx;
    __syncthreads();
    mx = fmaxf(mx, EX[(wave ^ 4) * 16 + l15]);

    float s = 0.f;
    #pragma unroll
    for (int j = 0; j < 28; ++j) {
        if (h == 0 || j < 21) {
            #pragma unroll
            for (int r = 0; r < 4; ++r) {
                float e = __expf(sacc[j][r] - mx);
                sacc[j][r] = e;
                s += e;
            }
        }
    }
    s += __shfl_xor(s, 16);
    s += __shfl_xor(s, 32);
    if (lane < 16) EX[128 + wave * 16 + l15] = s;
    __syncthreads();
    s += EX[128 + (wave ^ 4) * 16 + l15];
    const float ri = 1.f / s;

    const int pc = t >> 2, ps = t & 3;
    const bf16* sV  = c3b + (size_t)pc * MPAD + ((ps ^ ((pc >> 1) & 3)) * 8);
    const bf16* sV2 = c3b + (size_t)(pc + 128) * MPAD + ((ps ^ ((pc >> 1) & 3)) * 8);
    rXa = *(const uint4*)(sV);
    rXb = *(const uint4*)(sV2);

    {
        const int n = p * 16 + l15;
        const unsigned sw = (unsigned)((n & 7) << 4);
        const unsigned rowb = (unsigned)(n * 1792);
        #pragma unroll
        for (int j = 0; j < 28; ++j) {
            bf16x4 w;
            if (h == 0 || j < 21) {
                w = bf16x4{ (bf16)(sacc[j][0] * ri), (bf16)(sacc[j][1] * ri),
                            (bf16)(sacc[j][2] * ri), (bf16)(sacc[j][3] * ri) };
            } else {
                w = bf16x4{ (bf16)0.f, (bf16)0.f, (bf16)0.f, (bf16)0.f };
            }
            unsigned byte = rowb + (unsigned)(h * 896 + j * 32 + lg * 8);
            *(bf16x4*)(smem + (byte ^ sw)) = w;
        }
    }
    __syncthreads();

    *(uint4*)(stg + t * 16) = rXa;
    *(uint4*)(stg + 8192 + t * 16) = rXb;
    rYa = *(const uint4*)(sV + 32);
    rYb = *(const uint4*)(sV2 + 32);
    __syncthreads();

    const int wn = h, wq = p;
    f32x4 acc2[2][4];
    #pragma unroll
    for (int fn = 0; fn < 2; ++fn)
        #pragma unroll
        for (int fc = 0; fc < 4; ++fc) {
            f32x4 z = {0.f, 0.f, 0.f, 0.f};
            acc2[fn][fc] = z;
        }

    #pragma unroll
    for (int ks = 0; ks < 28; ++ks) {
        const unsigned char* bufc = stg + (ks & 1) * 16384;
        unsigned char* bufn = stg + ((ks & 1) ^ 1) * 16384;
        if (ks + 1 < 28) {
            if (ks & 1) { *(uint4*)(bufn + t * 16) = rXa; *(uint4*)(bufn + 8192 + t * 16) = rXb; }
            else        { *(uint4*)(bufn + t * 16) = rYa; *(uint4*)(bufn + 8192 + t * 16) = rYb; }
        }
        if (ks + 2 < 28) {
            if (ks & 1) { rYa = *(const uint4*)(sV + (ks + 2) * 32); rYb = *(const uint4*)(sV2 + (ks + 2) * 32); }
            else        { rXa = *(const uint4*)(sV + (ks + 2) * 32); rXb = *(const uint4*)(sV2 + (ks + 2) * 32); }
        }
        {
            int nA0 = wn * 32 + l15, nA1 = nA0 + 16;
            int mb = (ks * 32 + lg * 8) * 2;
            bf16x8 af0 = *(const bf16x8*)(smem + ((nA0 * 1792 + mb) ^ ((nA0 & 7) << 4)));
            bf16x8 af1 = *(const bf16x8*)(smem + ((nA1 * 1792 + mb) ^ ((nA1 & 7) << 4)));
            #pragma unroll
            for (int fc = 0; fc < 4; ++fc) {
                int c = wq * 64 + fc * 16 + l15;
                bf16x8 bfr = *(const bf16x8*)(bufc + c * 64 + ((lg ^ ((c >> 1) & 3)) * 16));
                acc2[0][fc] = __builtin_amdgcn_mfma_f32_16x16x32_bf16(af0, bfr, acc2[0][fc], 0, 0, 0);
                acc2[1][fc] = __builtin_amdgcn_mfma_f32_16x16x32_bf16(af1, bfr, acc2[1][fc], 0, 0, 0);
            }
        }
        __syncthreads();
    }

    float* R = (float*)smem;    // [64][257], P_lds dead
    #pragma unroll
    for (int fn = 0; fn < 2; ++fn)
        #pragma unroll
        for (int fc = 0; fc < 4; ++fc) {
            int c = wq * 64 + fc * 16 + l15;
            #pragma unroll
            for (int r = 0; r < 4; ++r) {
                int n = wn * 32 + fn * 16 + lg * 4 + r;
                R[n * 257 + c] = acc2[fn][fc][r];
            }
        }
    __syncthreads();
    const float g = gamma[0];
    const float* xb = x + (size_t)b * CIN * NPIX + n0;
    float* ob = out + (size_t)b * CIN * NPIX + n0;
    #pragma unroll 4
    for (int i = 0; i < 32; ++i) {
        int idx = t + i * 512;                  // 256 c x 64 n
        int c = idx >> 6, nn = idx & 63;
        size_t off = (size_t)c * NPIX + nn;
        ob[off] = g * R[nn * 257 + c] + xb[off];
    }
}

extern "C" void kernel_launch(void* const* d_in, const int* in_sizes, int n_in,
                              void* d_out, int out_size, void* d_ws, size_t ws_size,
                              hipStream_t stream) {
    const float* x     = (const float*)d_in[0];
    const float* W1    = (const float*)d_in[1];
    const float* W2    = (const float*)d_in[2];
    const float* W3    = (const float*)d_in[3];
    const float* gamma = (const float*)d_in[4];
    float* out = (float*)d_out;

    bf16* ws    = (bf16*)d_ws;
    bf16* WcatF = ws;                                      // 512*256 (frag-major)
    bf16* c2n   = WcatF + (size_t)512 * 256;               // 32*3136*128
    bf16* c1pT  = c2n + (size_t)BATCH * NPIX * CHALF;      // 32*896*128
    bf16* c3p   = c1pT + (size_t)BATCH * MPAD * CHALF;     // 32*256*896

    k_cast<<<64, 256, 0, stream>>>(W1, W2, W3, WcatF);
    k_conv<<<dim3(28, BATCH), 512, 0, stream>>>(x, WcatF, c2n, c1pT, c3p);
    k_attn<<<dim3(49, BATCH), 512, 0, stream>>>(c2n, c1pT, c3p, x, gamma, out);
}